// Round 9
// baseline (260.948 us; speedup 1.0000x reference)
//
#include <hip/hip_runtime.h>

typedef __bf16 bf16;
typedef __bf16 bf16x4 __attribute__((ext_vector_type(4)));
typedef __bf16 bf16x8 __attribute__((ext_vector_type(8)));
typedef float f32x4 __attribute__((ext_vector_type(4)));

__device__ inline float bfbits(unsigned u) { return __builtin_bit_cast(float, u); }

__device__ inline bf16x8 cvt8p(f32x4 x0, f32x4 x1) {
  bf16x8 a;
  a[0] = (bf16)x0[0]; a[1] = (bf16)x0[1]; a[2] = (bf16)x0[2]; a[3] = (bf16)x0[3];
  a[4] = (bf16)x1[0]; a[5] = (bf16)x1[1]; a[6] = (bf16)x1[2]; a[7] = (bf16)x1[3];
  return a;
}

#define MFMA16(a, b, c) __builtin_amdgcn_mfma_f32_16x16x32_bf16((a), (b), (c), 0, 0, 0)

// async global->LDS, 16B per lane; dest is wave-uniform base (+lane*16 in HW)
__device__ inline void gload16(const void* g, void* l) {
  __builtin_amdgcn_global_load_lds(
      (const __attribute__((address_space(1))) void*)g,
      (__attribute__((address_space(3))) void*)l, 16, 0, 0);
}

#define BARRIER()                      \
  do {                                 \
    asm volatile("" ::: "memory");     \
    __builtin_amdgcn_s_barrier();      \
    asm volatile("" ::: "memory");     \
  } while (0)

template <int N>
__device__ inline void waitcnt_vm() {
  asm volatile("s_waitcnt vmcnt(%0)" ::"i"(N) : "memory");
}

// ---------------------------------------------------------------------------
// Batched weight prep: f32 W[K][N] -> MFMA B-fragment-ordered bf16.
// mode 1: item-L1 concat map (row<128 ? row : row+256) for [tire|specs|tproj].
// ---------------------------------------------------------------------------
struct WEnt { const float* src; bf16* dst; int K; int N; int mode; int base; };
struct WprepArgs { WEnt e[9]; int nent; int total; float* zb; };

__global__ __launch_bounds__(256) void wprep_all(WprepArgs a) {
  int idx = blockIdx.x * 256 + threadIdx.x;
  if (idx < 128) a.zb[idx] = 0.0f;
  if (idx >= a.total) return;
  int ei = 0;
  while (ei + 1 < a.nent && idx >= a.e[ei + 1].base) ++ei;
  const WEnt E = a.e[ei];
  int li = idx - E.base;
  int lane = li & 63, fi = li >> 6;
  int NT = E.N / 16;
  int kt = fi / NT, nt = fi % NT;
  int krow = kt * 32 + ((lane >> 4) << 3);
  int col = nt * 16 + (lane & 15);
  bf16* d = E.dst + (size_t)li * 8;
#pragma unroll
  for (int j = 0; j < 8; ++j) {
    int r = krow + j;
    if (E.mode == 1) r = (r < 128) ? r : r + 256;
    d[j] = (bf16)E.src[(size_t)r * E.N + col];
  }
}

// ---------------------------------------------------------------------------
// Segment bounds: bound[u] = first index i with hsegs[i] >= u, u in [0,U].
// ---------------------------------------------------------------------------
__global__ __launch_bounds__(256) void seg_bounds(const int* __restrict__ hsegs,
                                                  int* __restrict__ bound, int E, int U) {
  int e = blockIdx.x * 256 + threadIdx.x;
  if (e > E) return;
  if (e == 0) {
    int b = hsegs[0];
    for (int u = 0; u <= b; ++u) bound[u] = 0;
  } else if (e == E) {
    int a = hsegs[E - 1];
    for (int u = a + 1; u <= U; ++u) bound[u] = E;
  } else {
    int a = hsegs[e - 1], b = hsegs[e];
    for (int u = a + 1; u <= b; ++u) bound[u] = e;
  }
}

// ---------------------------------------------------------------------------
// Generic small GEMM for brandC/sizeC (tiny grids), f32 out.
// ---------------------------------------------------------------------------
struct GemmArgs {
  const void* a0; const bf16* wfrag; const float* bias; void* out; int M;
};

template <int K, int N, int NW>
__global__ __launch_bounds__(NW * 64) void gemm_k(GemmArgs g) {
  constexpr int KT = K / 32, NT = N / 16;
  constexpr int TROWS = NW * 32;
  __shared__ bf16 wlds[K * N];
  {
    const uint4* s = (const uint4*)g.wfrag;
    uint4* d = (uint4*)wlds;
    constexpr int CH = K * N * 2 / 16;
    for (int i = threadIdx.x; i < CH; i += NW * 64) d[i] = s[i];
  }
  __syncthreads();

  const int lane = threadIdx.x & 63;
  const int wave = threadIdx.x >> 6;
  const int kgo = (lane >> 4) << 3;
  const int ntiles = (g.M + TROWS - 1) / TROWS;

  for (int tile = blockIdx.x; tile < ntiles; tile += gridDim.x) {
    const int rowbase = tile * TROWS;
    const int rw = rowbase + wave * 16 + (lane & 15);
    const int r0 = min(rw, g.M - 1);
    const int r1 = min(rw + NW * 16, g.M - 1);

    f32x4 acc[2][NT] = {};
#pragma unroll 2
    for (int kt = 0; kt < KT; ++kt) {
      const int kc = kt * 32 + kgo;
      const f32x4* q0 = (const f32x4*)((const float*)g.a0 + (size_t)r0 * K + kc);
      const f32x4* q1 = (const f32x4*)((const float*)g.a0 + (size_t)r1 * K + kc);
      bf16x8 a0 = cvt8p(q0[0], q0[1]);
      bf16x8 a1 = cvt8p(q1[0], q1[1]);
      const bf16x8* bp = ((const bf16x8*)wlds) + kt * NT * 64 + lane;
#pragma unroll
      for (int nt = 0; nt < NT; ++nt) {
        bf16x8 b = bp[nt * 64];
        acc[0][nt] = MFMA16(a0, b, acc[0][nt]);
        acc[1][nt] = MFMA16(a1, b, acc[1][nt]);
      }
    }

    const int colbase = lane & 15;
    const int rgrp = (lane >> 4) * 4;
#pragma unroll
    for (int m = 0; m < 2; ++m) {
      const int rbase = rowbase + m * (NW * 16) + wave * 16 + rgrp;
#pragma unroll
      for (int j = 0; j < 4; ++j) {
        const int r = rbase + j;
        if (r < g.M) {
#pragma unroll
          for (int nt = 0; nt < NT; ++nt) {
            float v = acc[m][nt][j] + g.bias[colbase + nt * 16];
            ((float*)g.out)[(size_t)r * N + colbase + nt * 16] = v;
          }
        }
      }
    }
  }
}

// ---------------------------------------------------------------------------
// Text projection (proven): staged A via global_load_lds dbuf, counted vmcnt,
// source-side XOR swizzle, B-frags from global L2. 32KB LDS, 16 waves/CU.
// ---------------------------------------------------------------------------
struct TpArgs { const float* text; const bf16* wf; const float* bias; bf16* out; int M; };

__global__ __launch_bounds__(256, 4) void tp_k(TpArgs g) {
  __shared__ float abuf[2][128 * 32];  // 2 x 16 KB
  const int tid = threadIdx.x, lane = tid & 63, wave = tid >> 6;
  const int kgo = (lane >> 4) << 3, colbase = lane & 15, r4 = (lane >> 4) * 4;
  const int rowbase = blockIdx.x << 7;

  auto stage = [&](int kt, int bi) {
#pragma unroll
    for (int i = 0; i < 4; ++i) {
      const int q = i * 256 + wave * 64 + lane;
      const int row = q >> 3;                     // 8 chunks(16B) per row
      const int c = (lane & 7) ^ (row & 7);       // pre-swizzled source chunk
      const int rg = min(rowbase + row, g.M - 1);
      const float* src = g.text + (size_t)rg * 384 + kt * 32 + c * 4;
      gload16(src, (char*)abuf[bi] + (size_t)(i * 256 + wave * 64) * 16);
    }
  };

  stage(0, 0);
  f32x4 acc[2][4] = {};
  for (int kt = 0; kt < 12; ++kt) {
    if (kt + 1 < 12) {
      stage(kt + 1, (kt + 1) & 1);
      waitcnt_vm<4>();
    } else {
      waitcnt_vm<0>();
    }
    BARRIER();
    const float* buf = abuf[kt & 1];
#pragma unroll
    for (int m = 0; m < 2; ++m) {
      const int row = m * 64 + wave * 16 + colbase;
      const int c0 = kgo >> 2;
      f32x4 x0 = *(const f32x4*)(buf + row * 32 + ((c0 ^ (row & 7)) << 2));
      f32x4 x1 = *(const f32x4*)(buf + row * 32 + (((c0 + 1) ^ (row & 7)) << 2));
      bf16x8 a = cvt8p(x0, x1);
      const bf16x8* bp = ((const bf16x8*)g.wf) + kt * 4 * 64 + lane;
#pragma unroll
      for (int nt = 0; nt < 4; ++nt)
        acc[m][nt] = MFMA16(a, bp[nt * 64], acc[m][nt]);
    }
    BARRIER();
  }

#pragma unroll
  for (int m = 0; m < 2; ++m) {
    const int rbase = rowbase + m * 64 + wave * 16 + r4;
#pragma unroll
    for (int j = 0; j < 4; ++j) {
      const int r = rbase + j;
      if (r < g.M) {
#pragma unroll
        for (int nt = 0; nt < 4; ++nt) {
          float v = fmaxf(acc[m][nt][j] + g.bias[colbase + nt * 16], 0.0f);
          g.out[(size_t)r * 64 + colbase + nt * 16] = (bf16)v;
        }
      }
    }
  }
}

// ---------------------------------------------------------------------------
// L1 kernel (tp_k-style): h1[M][128] bf16 = relu(concat @ W1 + bias-term).
// A staged per-kstep via global_load_lds dbuf (32KB), W1 frags from global L2.
// ASRC 2 = item [tire f32 | specs f32 | tproj bf16], KT1=8, FK=6, BS=1
// ASRC 3 = user [h_user f32 | pool bf16],            KT1=6, FK=4, BS=0
// ---------------------------------------------------------------------------
struct L1Args {
  const void* a0; const void* a1; const void* a2;
  const int* bidx; const int* sidx;
  const float* brandC; const float* sizeC;
  const bf16* wf1; const float* b1;
  bf16* out; int M;
};

template <int KT1, int ASRC, int BS>
__global__ __launch_bounds__(256, 4) void l1_k(L1Args g) {
  constexpr int FK = (ASRC == 2) ? 6 : 4;  // first bf16 kstep
  __shared__ char abuf[2][128 * 32 * 4];   // f32-kstep size; bf16 ksteps use half
  const int tid = threadIdx.x, lane = tid & 63, wave = tid >> 6;
  const int kgo = (lane >> 4) << 3, colbase = lane & 15, r4 = (lane >> 4) * 4;
  const int rowbase = blockIdx.x << 7;

  auto stage = [&](int kt, int bi) {
    if (kt < FK) {  // f32 source
#pragma unroll
      for (int i = 0; i < 4; ++i) {
        const int q = i * 256 + tid;
        const int row = q >> 3;
        const int c = (tid & 7) ^ (row & 7);
        const int rg = min(rowbase + row, g.M - 1);
        const float* src;
        if constexpr (ASRC == 2) {
          src = (kt < 4) ? (const float*)g.a0 + (size_t)rg * 128 + kt * 32 + c * 4
                         : (const float*)g.a1 + (size_t)rg * 64 + (kt - 4) * 32 + c * 4;
        } else {
          src = (const float*)g.a0 + (size_t)rg * 128 + kt * 32 + c * 4;
        }
        gload16(src, abuf[bi] + (size_t)q * 16);
      }
    } else {        // bf16 source
#pragma unroll
      for (int i = 0; i < 2; ++i) {
        const int q = i * 256 + tid;
        const int row = q >> 2;
        const int c = (tid & 3) ^ (row & 3);
        const int rg = min(rowbase + row, g.M - 1);
        const bf16* base = (const bf16*)((ASRC == 2) ? g.a2 : g.a1);
        const bf16* src = base + (size_t)rg * 64 + (kt - FK) * 32 + c * 8;
        gload16(src, abuf[bi] + (size_t)q * 16);
      }
    }
  };

  stage(0, 0);
  f32x4 acc[2][8] = {};
#pragma unroll
  for (int kt = 0; kt < KT1; ++kt) {
    if (kt + 1 < KT1) {
      stage(kt + 1, (kt + 1) & 1);
      if (kt + 1 < FK) waitcnt_vm<4>();
      else waitcnt_vm<2>();
    } else {
      waitcnt_vm<0>();
    }
    BARRIER();
    const char* buf = abuf[kt & 1];
#pragma unroll
    for (int m = 0; m < 2; ++m) {
      const int row = m * 64 + wave * 16 + colbase;
      bf16x8 a;
      if (kt < FK) {
        const float* bf = (const float*)buf;
        const int c0 = kgo >> 2;
        f32x4 x0 = *(const f32x4*)(bf + row * 32 + ((c0 ^ (row & 7)) << 2));
        f32x4 x1 = *(const f32x4*)(bf + row * 32 + (((c0 + 1) ^ (row & 7)) << 2));
        a = cvt8p(x0, x1);
      } else {
        const bf16* bb = (const bf16*)buf;
        const int c0 = kgo >> 3;
        a = *(const bf16x8*)(bb + row * 32 + ((c0 ^ (row & 3)) << 3));
      }
      const bf16x8* bp = ((const bf16x8*)g.wf1) + kt * 8 * 64 + lane;
#pragma unroll
      for (int nt = 0; nt < 8; ++nt)
        acc[m][nt] = MFMA16(a, bp[nt * 64], acc[m][nt]);
    }
    BARRIER();
  }

  // epilogue: bias (or brand/size gather) + relu -> h1 bf16
#pragma unroll
  for (int m = 0; m < 2; ++m) {
    const int rbase = rowbase + m * 64 + wave * 16 + r4;
#pragma unroll
    for (int j = 0; j < 4; ++j) {
      const int r = rbase + j;
      const float* bc = nullptr; const float* sc = nullptr;
      if constexpr (BS != 0) {
        const int rr = min(r, g.M - 1);
        bc = g.brandC + (size_t)g.bidx[rr] * 128;
        sc = g.sizeC + (size_t)g.sidx[rr] * 128;
      }
      if (r < g.M) {
#pragma unroll
        for (int nt = 0; nt < 8; ++nt) {
          const int col = colbase + nt * 16;
          float v = acc[m][nt][j];
          if constexpr (BS != 0) v += bc[col] + sc[col];
          else v += g.b1[col];
          g.out[(size_t)r * 128 + col] = (bf16)fmaxf(v, 0.0f);
        }
      }
    }
  }
}

// ---------------------------------------------------------------------------
// L2+L3 fused: h1 -> relu(h1@W2+b2) -> @W3+b3 -> l2norm -> f32 out (+bf16).
// Barrier-free: A per-lane from global h1 (L2/L3-hot), W2/W3 frags from L2,
// per-wave 4KB handoff tile only (16KB LDS total) -> 16 waves/CU.
// ---------------------------------------------------------------------------
struct L23Args {
  const bf16* h1; const bf16* wf2; const bf16* wf3;
  const float* b2; const float* b3;
  float* out; bf16* out2; int M;
};

__device__ inline bf16x8 read_afrag(const bf16* hw, int lane, int kt) {
  const int row = lane & 15;
  const int c8 = (kt * 4 + (lane >> 4)) ^ (row & 7);
  return *(const bf16x8*)(hw + row * 128 + c8 * 8);
}

__global__ __launch_bounds__(256, 4) void l23_k(L23Args g) {
  __shared__ bf16 ht[4][16 * 128];  // 16 KB
  const int tid = threadIdx.x, lane = tid & 63, wave = tid >> 6;
  const int kgo = (lane >> 4) << 3, colbase = lane & 15, r4 = (lane >> 4) * 4;
  const int rowbase = blockIdx.x << 7;
  bf16* hw = ht[wave];

  f32x4 acc3[2][4] = {};
#pragma unroll
  for (int m = 0; m < 2; ++m) {
    const int rw = rowbase + m * 64 + wave * 16 + colbase;
    const int r = min(rw, g.M - 1);
    bf16x8 a[4];
#pragma unroll
    for (int kt = 0; kt < 4; ++kt)
      a[kt] = *(const bf16x8*)(g.h1 + (size_t)r * 128 + kt * 32 + kgo);
    f32x4 acc2[8] = {};
#pragma unroll
    for (int kt = 0; kt < 4; ++kt) {
      const bf16x8* bp = ((const bf16x8*)g.wf2) + kt * 8 * 64 + lane;
#pragma unroll
      for (int nt = 0; nt < 8; ++nt)
        acc2[nt] = MFMA16(a[kt], bp[nt * 64], acc2[nt]);
    }
    // stage relu(h2) tile (per-wave, XOR-swizzled)
#pragma unroll
    for (int j = 0; j < 4; ++j) {
      const int row = r4 + j;
#pragma unroll
      for (int nt = 0; nt < 8; ++nt) {
        const int col = colbase + nt * 16;
        float v = fmaxf(acc2[nt][j] + g.b2[col], 0.0f);
        const int c8 = (col >> 3) ^ (row & 7);
        hw[row * 128 + c8 * 8 + (col & 7)] = (bf16)v;
      }
    }
    // L3 (W3 frags from global L2)
#pragma unroll
    for (int kt = 0; kt < 4; ++kt) {
      bf16x8 af = read_afrag(hw, lane, kt);
      const bf16x8* bq = ((const bf16x8*)g.wf3) + kt * 4 * 64 + lane;
#pragma unroll
      for (int nt = 0; nt < 4; ++nt)
        acc3[m][nt] = MFMA16(af, bq[nt * 64], acc3[m][nt]);
    }
  }

  // final epilogue: bias + l2norm + store
#pragma unroll
  for (int m = 0; m < 2; ++m) {
    const int rbase = rowbase + m * 64 + wave * 16 + r4;
#pragma unroll
    for (int j = 0; j < 4; ++j) {
      float vv[4];
      float ssq = 0.0f;
#pragma unroll
      for (int nt = 0; nt < 4; ++nt) {
        float v = acc3[m][nt][j] + g.b3[colbase + nt * 16];
        vv[nt] = v;
        ssq += v * v;
      }
      ssq += __shfl_xor(ssq, 1);
      ssq += __shfl_xor(ssq, 2);
      ssq += __shfl_xor(ssq, 4);
      ssq += __shfl_xor(ssq, 8);
      const float scale = 1.0f / fmaxf(sqrtf(ssq), 1e-12f);
      const int r = rbase + j;
      if (r < g.M) {
        float* o = g.out + (size_t)r * 64 + colbase;
#pragma unroll
        for (int nt = 0; nt < 4; ++nt) o[nt * 16] = vv[nt] * scale;
        if (g.out2) {
          bf16* o2 = g.out2 + (size_t)r * 64 + colbase;
#pragma unroll
          for (int nt = 0; nt < 4; ++nt) o2[nt * 16] = (bf16)(vv[nt] * scale);
        }
      }
    }
  }
}

// ---------------------------------------------------------------------------
// Segment-mean pooling: 16-lane groups, 16 gathers in flight per wave.
// ---------------------------------------------------------------------------
__global__ __launch_bounds__(256) void pool_k(const int* __restrict__ hitems,
                                              const int* __restrict__ bound,
                                              const bf16* __restrict__ itemb,
                                              bf16* __restrict__ pool, int U) {
  const int lane = threadIdx.x & 63;
  const int wid = blockIdx.x * 4 + (threadIdx.x >> 6);
  const int stride = gridDim.x * 4;
  const int grp = lane >> 4, li = lane & 15;
  for (int u = wid; u < U; u += stride) {
    const int s = bound[u], e = bound[u + 1];
    f32x4 s0 = {0.f, 0.f, 0.f, 0.f}, s1 = {0.f, 0.f, 0.f, 0.f};
    f32x4 s2 = {0.f, 0.f, 0.f, 0.f}, s3 = {0.f, 0.f, 0.f, 0.f};
    int i = s + grp;
    for (; i + 12 < e; i += 16) {
      int a0 = hitems[i], a1 = hitems[i + 4], a2 = hitems[i + 8], a3 = hitems[i + 12];
      uint2 r0 = *(const uint2*)(itemb + (size_t)a0 * 64 + li * 4);
      uint2 r1 = *(const uint2*)(itemb + (size_t)a1 * 64 + li * 4);
      uint2 r2 = *(const uint2*)(itemb + (size_t)a2 * 64 + li * 4);
      uint2 r3 = *(const uint2*)(itemb + (size_t)a3 * 64 + li * 4);
      s0[0] += bfbits(r0.x << 16); s0[1] += bfbits(r0.x & 0xffff0000u);
      s0[2] += bfbits(r0.y << 16); s0[3] += bfbits(r0.y & 0xffff0000u);
      s1[0] += bfbits(r1.x << 16); s1[1] += bfbits(r1.x & 0xffff0000u);
      s1[2] += bfbits(r1.y << 16); s1[3] += bfbits(r1.y & 0xffff0000u);
      s2[0] += bfbits(r2.x << 16); s2[1] += bfbits(r2.x & 0xffff0000u);
      s2[2] += bfbits(r2.y << 16); s2[3] += bfbits(r2.y & 0xffff0000u);
      s3[0] += bfbits(r3.x << 16); s3[1] += bfbits(r3.x & 0xffff0000u);
      s3[2] += bfbits(r3.y << 16); s3[3] += bfbits(r3.y & 0xffff0000u);
    }
    for (; i < e; i += 4) {
      int a0 = hitems[i];
      uint2 r0 = *(const uint2*)(itemb + (size_t)a0 * 64 + li * 4);
      s0[0] += bfbits(r0.x << 16); s0[1] += bfbits(r0.x & 0xffff0000u);
      s0[2] += bfbits(r0.y << 16); s0[3] += bfbits(r0.y & 0xffff0000u);
    }
#pragma unroll
    for (int c = 0; c < 4; ++c) s0[c] += s1[c] + s2[c] + s3[c];
#pragma unroll
    for (int c = 0; c < 4; ++c) {
      s0[c] += __shfl_xor(s0[c], 16);
      s0[c] += __shfl_xor(s0[c], 32);
    }
    const int cnt = e - s;
    const float inv = (cnt > 0) ? 1.0f / (float)cnt : 0.0f;
    if (grp == 0) {
      bf16x4 o;
      o[0] = (bf16)(s0[0] * inv); o[1] = (bf16)(s0[1] * inv);
      o[2] = (bf16)(s0[2] * inv); o[3] = (bf16)(s0[3] * inv);
      *(bf16x4*)(pool + (size_t)u * 64 + li * 4) = o;
    }
  }
}

// ---------------------------------------------------------------------------
extern "C" void kernel_launch(void* const* d_in, const int* in_sizes, int n_in,
                              void* d_out, int out_size, void* d_ws, size_t ws_size,
                              hipStream_t stream) {
  const float* h_user = (const float*)d_in[0];
  const float* h_tire = (const float*)d_in[1];
  const float* h_brand = (const float*)d_in[2];
  const float* h_size = (const float*)d_in[3];
  const float* specs = (const float*)d_in[4];
  const float* text = (const float*)d_in[5];
  const int* bidx = (const int*)d_in[6];
  const int* sidx = (const int*)d_in[7];
  const int* hitems = (const int*)d_in[8];
  const int* hsegs = (const int*)d_in[9];
  const float* W_tp = (const float*)d_in[10]; const float* b_tp = (const float*)d_in[11];
  const float* W_i1 = (const float*)d_in[12]; const float* b_i1 = (const float*)d_in[13];
  const float* W_i2 = (const float*)d_in[14]; const float* b_i2 = (const float*)d_in[15];
  const float* W_i3 = (const float*)d_in[16]; const float* b_i3 = (const float*)d_in[17];
  const float* W_u1 = (const float*)d_in[18]; const float* b_u1 = (const float*)d_in[19];
  const float* W_u2 = (const float*)d_in[20]; const float* b_u2 = (const float*)d_in[21];
  const float* W_u3 = (const float*)d_in[22]; const float* b_u3 = (const float*)d_in[23];

  const int U = in_sizes[0] / 128;   // 100000
  const int T = in_sizes[4] / 64;    // 100000
  const int E = in_sizes[8];         // 2000000

  char* ws = (char*)d_ws;
  size_t off = 0;
  auto alloc = [&](size_t bytes) -> char* {
    char* p = ws + off;
    off += (bytes + 255) & ~(size_t)255;
    return p;
  };
  bf16* wf_tp  = (bf16*)alloc(384 * 64 * 2);
  bf16* wf_i1a = (bf16*)alloc(256 * 128 * 2);
  bf16* wf_ib  = (bf16*)alloc(128 * 128 * 2);
  bf16* wf_is  = (bf16*)alloc(128 * 128 * 2);
  bf16* wf_i2  = (bf16*)alloc(128 * 128 * 2);
  bf16* wf_i3  = (bf16*)alloc(128 * 64 * 2);
  bf16* wf_u1  = (bf16*)alloc(192 * 128 * 2);
  bf16* wf_u2  = (bf16*)alloc(128 * 128 * 2);
  bf16* wf_u3  = (bf16*)alloc(128 * 64 * 2);
  float* zb    = (float*)alloc(128 * 4);
  float* brandC = (float*)alloc(100 * 128 * 4);
  float* sizeC  = (float*)alloc(500 * 128 * 4);
  bf16* tpbuf = (bf16*)alloc((size_t)T * 64 * 2);
  bf16* h1b   = (bf16*)alloc((size_t)T * 128 * 2);
  bf16* pool  = (bf16*)alloc((size_t)U * 64 * 2);
  bf16* itemb = (bf16*)alloc((size_t)T * 64 * 2);
  int* bound  = (int*)alloc((size_t)(U + 1) * 4);
  (void)ws_size; (void)n_in; (void)out_size;

  // --- batched weight prep ---
  WprepArgs wa = {};
  auto addent = [&](int i, const float* src, bf16* dst, int K, int N, int mode, int& run) {
    wa.e[i] = {src, dst, K, N, mode, run};
    run += (K / 32) * (N / 16) * 64;
  };
  int run = 0;
  addent(0, W_tp, wf_tp, 384, 64, 0, run);
  addent(1, W_i1, wf_i1a, 256, 128, 1, run);            // [tire|specs|tproj] rows
  addent(2, W_i1 + 128 * 128, wf_ib, 128, 128, 0, run); // brand rows
  addent(3, W_i1 + 256 * 128, wf_is, 128, 128, 0, run); // size rows
  addent(4, W_i2, wf_i2, 128, 128, 0, run);
  addent(5, W_i3, wf_i3, 128, 64, 0, run);
  addent(6, W_u1, wf_u1, 192, 128, 0, run);
  addent(7, W_u2, wf_u2, 128, 128, 0, run);
  addent(8, W_u3, wf_u3, 128, 64, 0, run);
  wa.nent = 9; wa.total = run; wa.zb = zb;
  wprep_all<<<(run + 255) / 256, 256, 0, stream>>>(wa);

  seg_bounds<<<(E + 256) / 256, 256, 0, stream>>>(hsegs, bound, E, U);

  {  // brandC[100][128] = h_brand @ W_i1[128:256] + b_i1 (bias folded)
    GemmArgs a = {}; a.a0 = h_brand; a.wfrag = wf_ib; a.bias = b_i1; a.out = brandC; a.M = 100;
    gemm_k<128, 128, 4><<<1, 256, 0, stream>>>(a);
  }
  {  // sizeC[500][128] = h_size @ W_i1[256:384] (zero bias)
    GemmArgs a = {}; a.a0 = h_size; a.wfrag = wf_is; a.bias = zb; a.out = sizeC; a.M = 500;
    gemm_k<128, 128, 4><<<4, 256, 0, stream>>>(a);
  }
  {  // text projection (staged)
    TpArgs a = {text, wf_tp, b_tp, tpbuf, T};
    tp_k<<<(T + 127) / 128, 256, 0, stream>>>(a);
  }

  float* out_user = (float*)d_out;
  float* out_item = out_user + (size_t)U * 64;
  const int tilesT = (T + 127) / 128;
  const int tilesU = (U + 127) / 128;

  {  // item L1 (staged, high occupancy)
    L1Args a = {};
    a.a0 = h_tire; a.a1 = specs; a.a2 = tpbuf;
    a.bidx = bidx; a.sidx = sidx; a.brandC = brandC; a.sizeC = sizeC;
    a.wf1 = wf_i1a; a.b1 = zb; a.out = h1b; a.M = T;
    l1_k<8, 2, 1><<<tilesT, 256, 0, stream>>>(a);
  }
  {  // item L2+L3 + l2norm (barrier-free)
    L23Args a = {};
    a.h1 = h1b; a.wf2 = wf_i2; a.wf3 = wf_i3; a.b2 = b_i2; a.b3 = b_i3;
    a.out = out_item; a.out2 = itemb; a.M = T;
    l23_k<<<tilesT, 256, 0, stream>>>(a);
  }

  pool_k<<<(U + 3) / 4, 256, 0, stream>>>(hitems, bound, itemb, pool, U);

  {  // user L1
    L1Args a = {};
    a.a0 = h_user; a.a1 = pool;
    a.wf1 = wf_u1; a.b1 = b_u1; a.out = h1b; a.M = U;
    l1_k<6, 3, 0><<<tilesU, 256, 0, stream>>>(a);
  }
  {  // user L2+L3 + l2norm
    L23Args a = {};
    a.h1 = h1b; a.wf2 = wf_u2; a.wf3 = wf_u3; a.b2 = b_u2; a.b3 = b_u3;
    a.out = out_user; a.out2 = nullptr; a.M = U;
    l23_k<<<tilesU, 256, 0, stream>>>(a);
  }
}

// Round 11
// 235.941 us; speedup vs baseline: 1.1060x; 1.1060x over previous
//
#include <hip/hip_runtime.h>

typedef __bf16 bf16;
typedef __bf16 bf16x4 __attribute__((ext_vector_type(4)));
typedef __bf16 bf16x8 __attribute__((ext_vector_type(8)));
typedef float f32x4 __attribute__((ext_vector_type(4)));

__device__ inline float bfbits(unsigned u) { return __builtin_bit_cast(float, u); }

__device__ inline bf16x8 cvt8p(f32x4 x0, f32x4 x1) {
  bf16x8 a;
  a[0] = (bf16)x0[0]; a[1] = (bf16)x0[1]; a[2] = (bf16)x0[2]; a[3] = (bf16)x0[3];
  a[4] = (bf16)x1[0]; a[5] = (bf16)x1[1]; a[6] = (bf16)x1[2]; a[7] = (bf16)x1[3];
  return a;
}
__device__ inline bf16x8 cvt8(const float* p) {
  const f32x4* q = (const f32x4*)p;
  return cvt8p(q[0], q[1]);
}

#define MFMA16(a, b, c) __builtin_amdgcn_mfma_f32_16x16x32_bf16((a), (b), (c), 0, 0, 0)

// async global->LDS, 16B per lane; dest is wave-uniform base (+lane*16 in HW)
__device__ inline void gload16(const void* g, void* l) {
  __builtin_amdgcn_global_load_lds(
      (const __attribute__((address_space(1))) void*)g,
      (__attribute__((address_space(3))) void*)l, 16, 0, 0);
}

#define BARRIER()                      \
  do {                                 \
    asm volatile("" ::: "memory");     \
    __builtin_amdgcn_s_barrier();      \
    asm volatile("" ::: "memory");     \
  } while (0)

template <int N>
__device__ inline void waitcnt_vm() {
  asm volatile("s_waitcnt vmcnt(%0)" ::"i"(N) : "memory");
}

// ---------------------------------------------------------------------------
// Batched weight prep: f32 W[K][N] -> MFMA B-fragment-ordered bf16.
// mode 1: item-L1 concat map (row<128 ? row : row+256) for [tire|specs|tproj].
// ---------------------------------------------------------------------------
struct WEnt { const float* src; bf16* dst; int K; int N; int mode; int base; };
struct WprepArgs { WEnt e[9]; int nent; int total; float* zb; };

__global__ __launch_bounds__(256) void wprep_all(WprepArgs a) {
  int idx = blockIdx.x * 256 + threadIdx.x;
  if (idx < 128) a.zb[idx] = 0.0f;
  if (idx >= a.total) return;
  int ei = 0;
  while (ei + 1 < a.nent && idx >= a.e[ei + 1].base) ++ei;
  const WEnt E = a.e[ei];
  int li = idx - E.base;
  int lane = li & 63, fi = li >> 6;
  int NT = E.N / 16;
  int kt = fi / NT, nt = fi % NT;
  int krow = kt * 32 + ((lane >> 4) << 3);
  int col = nt * 16 + (lane & 15);
  bf16* d = E.dst + (size_t)li * 8;
#pragma unroll
  for (int j = 0; j < 8; ++j) {
    int r = krow + j;
    if (E.mode == 1) r = (r < 128) ? r : r + 256;
    d[j] = (bf16)E.src[(size_t)r * E.N + col];
  }
}

// ---------------------------------------------------------------------------
// Segment bounds: bound[u] = first index i with hsegs[i] >= u, u in [0,U].
// ---------------------------------------------------------------------------
__global__ __launch_bounds__(256) void seg_bounds(const int* __restrict__ hsegs,
                                                  int* __restrict__ bound, int E, int U) {
  int e = blockIdx.x * 256 + threadIdx.x;
  if (e > E) return;
  if (e == 0) {
    int b = hsegs[0];
    for (int u = 0; u <= b; ++u) bound[u] = 0;
  } else if (e == E) {
    int a = hsegs[E - 1];
    for (int u = a + 1; u <= U; ++u) bound[u] = E;
  } else {
    int a = hsegs[e - 1], b = hsegs[e];
    for (int u = a + 1; u <= b; ++u) bound[u] = e;
  }
}

// ---------------------------------------------------------------------------
// Generic small GEMM for brandC/sizeC (tiny grids), f32 out.
// ---------------------------------------------------------------------------
struct GemmArgs {
  const void* a0; const bf16* wfrag; const float* bias; void* out; int M;
};

template <int K, int N, int NW>
__global__ __launch_bounds__(NW * 64) void gemm_k(GemmArgs g) {
  constexpr int KT = K / 32, NT = N / 16;
  constexpr int TROWS = NW * 32;
  __shared__ bf16 wlds[K * N];
  {
    const uint4* s = (const uint4*)g.wfrag;
    uint4* d = (uint4*)wlds;
    constexpr int CH = K * N * 2 / 16;
    for (int i = threadIdx.x; i < CH; i += NW * 64) d[i] = s[i];
  }
  __syncthreads();

  const int lane = threadIdx.x & 63;
  const int wave = threadIdx.x >> 6;
  const int kgo = (lane >> 4) << 3;
  const int ntiles = (g.M + TROWS - 1) / TROWS;

  for (int tile = blockIdx.x; tile < ntiles; tile += gridDim.x) {
    const int rowbase = tile * TROWS;
    const int rw = rowbase + wave * 16 + (lane & 15);
    const int r0 = min(rw, g.M - 1);
    const int r1 = min(rw + NW * 16, g.M - 1);

    f32x4 acc[2][NT] = {};
#pragma unroll 2
    for (int kt = 0; kt < KT; ++kt) {
      const int kc = kt * 32 + kgo;
      bf16x8 a0 = cvt8((const float*)g.a0 + (size_t)r0 * K + kc);
      bf16x8 a1 = cvt8((const float*)g.a0 + (size_t)r1 * K + kc);
      const bf16x8* bp = ((const bf16x8*)wlds) + kt * NT * 64 + lane;
#pragma unroll
      for (int nt = 0; nt < NT; ++nt) {
        bf16x8 b = bp[nt * 64];
        acc[0][nt] = MFMA16(a0, b, acc[0][nt]);
        acc[1][nt] = MFMA16(a1, b, acc[1][nt]);
      }
    }

    const int colbase = lane & 15;
    const int rgrp = (lane >> 4) * 4;
#pragma unroll
    for (int m = 0; m < 2; ++m) {
      const int rbase = rowbase + m * (NW * 16) + wave * 16 + rgrp;
#pragma unroll
      for (int j = 0; j < 4; ++j) {
        const int r = rbase + j;
        if (r < g.M) {
#pragma unroll
          for (int nt = 0; nt < NT; ++nt) {
            float v = acc[m][nt][j] + g.bias[colbase + nt * 16];
            ((float*)g.out)[(size_t)r * N + colbase + nt * 16] = v;
          }
        }
      }
    }
  }
}

// ---------------------------------------------------------------------------
// Text projection (R8/R9-proven, verbatim): staged A via global_load_lds dbuf
// + counted vmcnt(4), source-side XOR swizzle, B-frags from global L2.
// 32KB LDS, 16 waves/CU.
// ---------------------------------------------------------------------------
struct TpArgs { const float* text; const bf16* wf; const float* bias; bf16* out; int M; };

__global__ __launch_bounds__(256, 4) void tp_k(TpArgs g) {
  __shared__ float abuf[2][128 * 32];  // 2 x 16 KB
  const int tid = threadIdx.x, lane = tid & 63, wave = tid >> 6;
  const int kgo = (lane >> 4) << 3, colbase = lane & 15, r4 = (lane >> 4) * 4;
  const int rowbase = blockIdx.x << 7;

  auto stage = [&](int kt, int bi) {
#pragma unroll
    for (int i = 0; i < 4; ++i) {
      const int q = i * 256 + wave * 64 + lane;
      const int row = q >> 3;                     // 8 chunks(16B) per row
      const int c = (lane & 7) ^ (row & 7);       // pre-swizzled source chunk
      const int rg = min(rowbase + row, g.M - 1);
      const float* src = g.text + (size_t)rg * 384 + kt * 32 + c * 4;
      gload16(src, (char*)abuf[bi] + (size_t)(i * 256 + wave * 64) * 16);
    }
  };

  stage(0, 0);
  f32x4 acc[2][4] = {};
  for (int kt = 0; kt < 12; ++kt) {
    if (kt + 1 < 12) {
      stage(kt + 1, (kt + 1) & 1);
      waitcnt_vm<4>();
    } else {
      waitcnt_vm<0>();
    }
    BARRIER();
    const float* buf = abuf[kt & 1];
#pragma unroll
    for (int m = 0; m < 2; ++m) {
      const int row = m * 64 + wave * 16 + colbase;
      const int c0 = kgo >> 2;
      f32x4 x0 = *(const f32x4*)(buf + row * 32 + ((c0 ^ (row & 7)) << 2));
      f32x4 x1 = *(const f32x4*)(buf + row * 32 + (((c0 + 1) ^ (row & 7)) << 2));
      bf16x8 a = cvt8p(x0, x1);
      const bf16x8* bp = ((const bf16x8*)g.wf) + kt * 4 * 64 + lane;
#pragma unroll
      for (int nt = 0; nt < 4; ++nt)
        acc[m][nt] = MFMA16(a, bp[nt * 64], acc[m][nt]);
    }
    BARRIER();
  }

#pragma unroll
  for (int m = 0; m < 2; ++m) {
    const int rbase = rowbase + m * 64 + wave * 16 + r4;
#pragma unroll
    for (int j = 0; j < 4; ++j) {
      const int r = rbase + j;
      if (r < g.M) {
#pragma unroll
        for (int nt = 0; nt < 4; ++nt) {
          float v = fmaxf(acc[m][nt][j] + g.bias[colbase + nt * 16], 0.0f);
          g.out[(size_t)r * 64 + colbase + nt * 16] = (bf16)v;
        }
      }
    }
  }
}

// ---------------------------------------------------------------------------
// Fused 3-layer tower (R3-proven verbatim). One wave owns 2 groups of 16 rows.
// Layer handoff via per-wave 16x128 XOR-swizzled LDS tile; W1/W2/W3 in LDS.
// ASRC 2 = item concat [h_tire(128)|specs(64)|tproj(64)], K1=256
// ASRC 3 = user concat [h_user(128)|pool(64)], K1=192
// BS: add gathered brandC/sizeC (b1 pre-folded into brandC) in L1 epilogue.
// ---------------------------------------------------------------------------
struct TowerArgs {
  const void* a0; const void* a1; const void* a2;
  const int* bidx; const int* sidx;
  const float* brandC; const float* sizeC;
  const bf16* wf1; const bf16* wf2; const bf16* wf3;
  const float* b1; const float* b2; const float* b3;
  float* out; bf16* out2; int M;
};

template <int ASRC>
__device__ inline bf16x8 tower_load_a(const TowerArgs& g, int r, int kc) {
  if constexpr (ASRC == 2) {
    if (kc < 128) return cvt8((const float*)g.a0 + (size_t)r * 128 + kc);
    else if (kc < 192) return cvt8((const float*)g.a1 + (size_t)r * 64 + (kc - 128));
    else return *(const bf16x8*)((const bf16*)g.a2 + (size_t)r * 64 + (kc - 192));
  } else {
    if (kc < 128) return cvt8((const float*)g.a0 + (size_t)r * 128 + kc);
    else return *(const bf16x8*)((const bf16*)g.a1 + (size_t)r * 64 + (kc - 128));
  }
}

__device__ inline bf16x8 read_afrag(const bf16* hw, int lane, int kt) {
  const int row = lane & 15;
  const int c8 = (kt * 4 + (lane >> 4)) ^ (row & 7);
  return *(const bf16x8*)(hw + row * 128 + c8 * 8);
}

template <int K1, int ASRC, int BS>
__global__ __launch_bounds__(512, 2) void tower_k(TowerArgs g) {
  constexpr int KT1 = K1 / 32;
  constexpr int NW = 8;
  constexpr int TROWS = NW * 32;  // 256
  __shared__ bf16 lds[K1 * 128 + 128 * 128 + 128 * 64 + NW * 16 * 128];
  bf16* w1 = lds;
  bf16* w2 = lds + K1 * 128;
  bf16* w3 = w2 + 128 * 128;
  bf16* ht = w3 + 128 * 64;
  {
    const int tid = threadIdx.x;
    const uint4* s1 = (const uint4*)g.wf1; uint4* d1 = (uint4*)w1;
    for (int i = tid; i < K1 * 128 * 2 / 16; i += 512) d1[i] = s1[i];
    const uint4* s2 = (const uint4*)g.wf2; uint4* d2 = (uint4*)w2;
    for (int i = tid; i < 128 * 128 * 2 / 16; i += 512) d2[i] = s2[i];
    const uint4* s3 = (const uint4*)g.wf3; uint4* d3 = (uint4*)w3;
    for (int i = tid; i < 128 * 64 * 2 / 16; i += 512) d3[i] = s3[i];
  }
  __syncthreads();

  const int lane = threadIdx.x & 63;
  const int wave = threadIdx.x >> 6;
  const int kgo = (lane >> 4) << 3;
  const int colbase = lane & 15;
  const int r4 = (lane >> 4) * 4;
  bf16* hw = ht + wave * (16 * 128);
  const int ntiles = (g.M + TROWS - 1) / TROWS;

  for (int tile = blockIdx.x; tile < ntiles; tile += gridDim.x) {
    const int rowbase = tile * TROWS;
    const int rw = rowbase + wave * 16 + colbase;
    const int r0 = min(rw, g.M - 1);
    const int r1 = min(rw + NW * 16, g.M - 1);

    // ---- L1 ----
    f32x4 acc1[2][8] = {};
#pragma unroll 2
    for (int kt = 0; kt < KT1; ++kt) {
      const int kc = kt * 32 + kgo;
      bf16x8 a0 = tower_load_a<ASRC>(g, r0, kc);
      bf16x8 a1 = tower_load_a<ASRC>(g, r1, kc);
      const bf16x8* bp = ((const bf16x8*)w1) + kt * 8 * 64 + lane;
#pragma unroll
      for (int nt = 0; nt < 8; ++nt) {
        bf16x8 b = bp[nt * 64];
        acc1[0][nt] = MFMA16(a0, b, acc1[0][nt]);
        acc1[1][nt] = MFMA16(a1, b, acc1[1][nt]);
      }
    }

    f32x4 acc3[2][4] = {};
#pragma unroll
    for (int m = 0; m < 2; ++m) {
      const int rbase = rowbase + m * (NW * 16) + wave * 16 + r4;
      // L1 epilogue -> stage bf16 h1 tile (per-wave, swizzled)
#pragma unroll
      for (int j = 0; j < 4; ++j) {
        const int row = r4 + j;
        const float* bc = nullptr; const float* sc = nullptr;
        if constexpr (BS != 0) {
          const int rr = min(rbase + j, g.M - 1);
          bc = g.brandC + (size_t)g.bidx[rr] * 128;
          sc = g.sizeC + (size_t)g.sidx[rr] * 128;
        }
#pragma unroll
        for (int nt = 0; nt < 8; ++nt) {
          const int col = colbase + nt * 16;
          float v = acc1[m][nt][j];
          if constexpr (BS != 0) v += bc[col] + sc[col];
          else v += g.b1[col];
          v = fmaxf(v, 0.0f);
          const int c8 = (col >> 3) ^ (row & 7);
          hw[row * 128 + c8 * 8 + (col & 7)] = (bf16)v;
        }
      }
      // ---- L2 ----
      f32x4 acc2[8] = {};
#pragma unroll
      for (int kt = 0; kt < 4; ++kt) {
        bf16x8 a = read_afrag(hw, lane, kt);
        const bf16x8* bp = ((const bf16x8*)w2) + kt * 8 * 64 + lane;
#pragma unroll
        for (int nt = 0; nt < 8; ++nt)
          acc2[nt] = MFMA16(a, bp[nt * 64], acc2[nt]);
      }
      // L2 epilogue -> stage h2 tile
#pragma unroll
      for (int j = 0; j < 4; ++j) {
        const int row = r4 + j;
#pragma unroll
        for (int nt = 0; nt < 8; ++nt) {
          const int col = colbase + nt * 16;
          float v = fmaxf(acc2[nt][j] + g.b2[col], 0.0f);
          const int c8 = (col >> 3) ^ (row & 7);
          hw[row * 128 + c8 * 8 + (col & 7)] = (bf16)v;
        }
      }
      // ---- L3 ----
#pragma unroll
      for (int kt = 0; kt < 4; ++kt) {
        bf16x8 a = read_afrag(hw, lane, kt);
        const bf16x8* bp = ((const bf16x8*)w3) + kt * 4 * 64 + lane;
#pragma unroll
        for (int nt = 0; nt < 4; ++nt)
          acc3[m][nt] = MFMA16(a, bp[nt * 64], acc3[m][nt]);
      }
    }

    // ---- final epilogue: bias + l2norm + store ----
#pragma unroll
    for (int m = 0; m < 2; ++m) {
      const int rbase = rowbase + m * (NW * 16) + wave * 16 + r4;
#pragma unroll
      for (int j = 0; j < 4; ++j) {
        float vv[4];
        float ssq = 0.0f;
#pragma unroll
        for (int nt = 0; nt < 4; ++nt) {
          float v = acc3[m][nt][j] + g.b3[colbase + nt * 16];
          vv[nt] = v;
          ssq += v * v;
        }
        ssq += __shfl_xor(ssq, 1);
        ssq += __shfl_xor(ssq, 2);
        ssq += __shfl_xor(ssq, 4);
        ssq += __shfl_xor(ssq, 8);
        const float scale = 1.0f / fmaxf(sqrtf(ssq), 1e-12f);
        const int r = rbase + j;
        if (r < g.M) {
          float* o = g.out + (size_t)r * 64 + colbase;
#pragma unroll
          for (int nt = 0; nt < 4; ++nt) o[nt * 16] = vv[nt] * scale;
          if (g.out2) {
            bf16* o2 = g.out2 + (size_t)r * 64 + colbase;
#pragma unroll
            for (int nt = 0; nt < 4; ++nt) o2[nt * 16] = (bf16)(vv[nt] * scale);
          }
        }
      }
    }
  }
}

// ---------------------------------------------------------------------------
// Segment-mean pooling: 16-lane groups, 16 gathers in flight per wave.
// ---------------------------------------------------------------------------
__global__ __launch_bounds__(256) void pool_k(const int* __restrict__ hitems,
                                              const int* __restrict__ bound,
                                              const bf16* __restrict__ itemb,
                                              bf16* __restrict__ pool, int U) {
  const int lane = threadIdx.x & 63;
  const int wid = blockIdx.x * 4 + (threadIdx.x >> 6);
  const int stride = gridDim.x * 4;
  const int grp = lane >> 4, li = lane & 15;
  for (int u = wid; u < U; u += stride) {
    const int s = bound[u], e = bound[u + 1];
    f32x4 s0 = {0.f, 0.f, 0.f, 0.f}, s1 = {0.f, 0.f, 0.f, 0.f};
    f32x4 s2 = {0.f, 0.f, 0.f, 0.f}, s3 = {0.f, 0.f, 0.f, 0.f};
    int i = s + grp;
    for (; i + 12 < e; i += 16) {
      int a0 = hitems[i], a1 = hitems[i + 4], a2 = hitems[i + 8], a3 = hitems[i + 12];
      uint2 r0 = *(const uint2*)(itemb + (size_t)a0 * 64 + li * 4);
      uint2 r1 = *(const uint2*)(itemb + (size_t)a1 * 64 + li * 4);
      uint2 r2 = *(const uint2*)(itemb + (size_t)a2 * 64 + li * 4);
      uint2 r3 = *(const uint2*)(itemb + (size_t)a3 * 64 + li * 4);
      s0[0] += bfbits(r0.x << 16); s0[1] += bfbits(r0.x & 0xffff0000u);
      s0[2] += bfbits(r0.y << 16); s0[3] += bfbits(r0.y & 0xffff0000u);
      s1[0] += bfbits(r1.x << 16); s1[1] += bfbits(r1.x & 0xffff0000u);
      s1[2] += bfbits(r1.y << 16); s1[3] += bfbits(r1.y & 0xffff0000u);
      s2[0] += bfbits(r2.x << 16); s2[1] += bfbits(r2.x & 0xffff0000u);
      s2[2] += bfbits(r2.y << 16); s2[3] += bfbits(r2.y & 0xffff0000u);
      s3[0] += bfbits(r3.x << 16); s3[1] += bfbits(r3.x & 0xffff0000u);
      s3[2] += bfbits(r3.y << 16); s3[3] += bfbits(r3.y & 0xffff0000u);
    }
    for (; i < e; i += 4) {
      int a0 = hitems[i];
      uint2 r0 = *(const uint2*)(itemb + (size_t)a0 * 64 + li * 4);
      s0[0] += bfbits(r0.x << 16); s0[1] += bfbits(r0.x & 0xffff0000u);
      s0[2] += bfbits(r0.y << 16); s0[3] += bfbits(r0.y & 0xffff0000u);
    }
#pragma unroll
    for (int c = 0; c < 4; ++c) s0[c] += s1[c] + s2[c] + s3[c];
#pragma unroll
    for (int c = 0; c < 4; ++c) {
      s0[c] += __shfl_xor(s0[c], 16);
      s0[c] += __shfl_xor(s0[c], 32);
    }
    const int cnt = e - s;
    const float inv = (cnt > 0) ? 1.0f / (float)cnt : 0.0f;
    if (grp == 0) {
      bf16x4 o;
      o[0] = (bf16)(s0[0] * inv); o[1] = (bf16)(s0[1] * inv);
      o[2] = (bf16)(s0[2] * inv); o[3] = (bf16)(s0[3] * inv);
      *(bf16x4*)(pool + (size_t)u * 64 + li * 4) = o;
    }
  }
}

// ---------------------------------------------------------------------------
extern "C" void kernel_launch(void* const* d_in, const int* in_sizes, int n_in,
                              void* d_out, int out_size, void* d_ws, size_t ws_size,
                              hipStream_t stream) {
  const float* h_user = (const float*)d_in[0];
  const float* h_tire = (const float*)d_in[1];
  const float* h_brand = (const float*)d_in[2];
  const float* h_size = (const float*)d_in[3];
  const float* specs = (const float*)d_in[4];
  const float* text = (const float*)d_in[5];
  const int* bidx = (const int*)d_in[6];
  const int* sidx = (const int*)d_in[7];
  const int* hitems = (const int*)d_in[8];
  const int* hsegs = (const int*)d_in[9];
  const float* W_tp = (const float*)d_in[10]; const float* b_tp = (const float*)d_in[11];
  const float* W_i1 = (const float*)d_in[12]; const float* b_i1 = (const float*)d_in[13];
  const float* W_i2 = (const float*)d_in[14]; const float* b_i2 = (const float*)d_in[15];
  const float* W_i3 = (const float*)d_in[16]; const float* b_i3 = (const float*)d_in[17];
  const float* W_u1 = (const float*)d_in[18]; const float* b_u1 = (const float*)d_in[19];
  const float* W_u2 = (const float*)d_in[20]; const float* b_u2 = (const float*)d_in[21];
  const float* W_u3 = (const float*)d_in[22]; const float* b_u3 = (const float*)d_in[23];

  const int U = in_sizes[0] / 128;   // 100000
  const int T = in_sizes[4] / 64;    // 100000
  const int E = in_sizes[8];         // 2000000

  char* ws = (char*)d_ws;
  size_t off = 0;
  auto alloc = [&](size_t bytes) -> char* {
    char* p = ws + off;
    off += (bytes + 255) & ~(size_t)255;
    return p;
  };
  bf16* wf_tp  = (bf16*)alloc(384 * 64 * 2);
  bf16* wf_i1a = (bf16*)alloc(256 * 128 * 2);
  bf16* wf_ib  = (bf16*)alloc(128 * 128 * 2);
  bf16* wf_is  = (bf16*)alloc(128 * 128 * 2);
  bf16* wf_i2  = (bf16*)alloc(128 * 128 * 2);
  bf16* wf_i3  = (bf16*)alloc(128 * 64 * 2);
  bf16* wf_u1  = (bf16*)alloc(192 * 128 * 2);
  bf16* wf_u2  = (bf16*)alloc(128 * 128 * 2);
  bf16* wf_u3  = (bf16*)alloc(128 * 64 * 2);
  float* zb    = (float*)alloc(128 * 4);
  float* brandC = (float*)alloc(100 * 128 * 4);
  float* sizeC  = (float*)alloc(500 * 128 * 4);
  bf16* tpbuf = (bf16*)alloc((size_t)T * 64 * 2);
  bf16* pool  = (bf16*)alloc((size_t)U * 64 * 2);
  bf16* itemb = (bf16*)alloc((size_t)T * 64 * 2);
  int* bound  = (int*)alloc((size_t)(U + 1) * 4);
  (void)ws_size; (void)n_in; (void)out_size;

  // --- batched weight prep ---
  WprepArgs wa = {};
  auto addent = [&](int i, const float* src, bf16* dst, int K, int N, int mode, int& run) {
    wa.e[i] = {src, dst, K, N, mode, run};
    run += (K / 32) * (N / 16) * 64;
  };
  int run = 0;
  addent(0, W_tp, wf_tp, 384, 64, 0, run);
  addent(1, W_i1, wf_i1a, 256, 128, 1, run);            // [tire|specs|tproj] rows
  addent(2, W_i1 + 128 * 128, wf_ib, 128, 128, 0, run); // brand rows
  addent(3, W_i1 + 256 * 128, wf_is, 128, 128, 0, run); // size rows
  addent(4, W_i2, wf_i2, 128, 128, 0, run);
  addent(5, W_i3, wf_i3, 128, 64, 0, run);
  addent(6, W_u1, wf_u1, 192, 128, 0, run);
  addent(7, W_u2, wf_u2, 128, 128, 0, run);
  addent(8, W_u3, wf_u3, 128, 64, 0, run);
  wa.nent = 9; wa.total = run; wa.zb = zb;
  wprep_all<<<(run + 255) / 256, 256, 0, stream>>>(wa);

  seg_bounds<<<(E + 256) / 256, 256, 0, stream>>>(hsegs, bound, E, U);

  {  // brandC[100][128] = h_brand @ W_i1[128:256] + b_i1 (bias folded)
    GemmArgs a = {}; a.a0 = h_brand; a.wfrag = wf_ib; a.bias = b_i1; a.out = brandC; a.M = 100;
    gemm_k<128, 128, 4><<<1, 256, 0, stream>>>(a);
  }
  {  // sizeC[500][128] = h_size @ W_i1[256:384] (zero bias)
    GemmArgs a = {}; a.a0 = h_size; a.wfrag = wf_is; a.bias = zb; a.out = sizeC; a.M = 500;
    gemm_k<128, 128, 4><<<4, 256, 0, stream>>>(a);
  }
  {  // text projection (staged global_load_lds, R8/R9-proven)
    TpArgs a = {text, wf_tp, b_tp, tpbuf, T};
    tp_k<<<(T + 127) / 128, 256, 0, stream>>>(a);
  }

  float* out_user = (float*)d_out;
  float* out_item = out_user + (size_t)U * 64;

  {  // fused item tower (R3-proven)
    TowerArgs a = {};
    a.a0 = h_tire; a.a1 = specs; a.a2 = tpbuf;
    a.bidx = bidx; a.sidx = sidx; a.brandC = brandC; a.sizeC = sizeC;
    a.wf1 = wf_i1a; a.wf2 = wf_i2; a.wf3 = wf_i3;
    a.b1 = zb; a.b2 = b_i2; a.b3 = b_i3;
    a.out = out_item; a.out2 = itemb; a.M = T;
    tower_k<256, 2, 1><<<(T + 255) / 256, 512, 0, stream>>>(a);
  }

  pool_k<<<(U + 3) / 4, 256, 0, stream>>>(hitems, bound, itemb, pool, U);

  {  // fused user tower (R3-proven)
    TowerArgs a = {};
    a.a0 = h_user; a.a1 = pool;
    a.wf1 = wf_u1; a.wf2 = wf_u2; a.wf3 = wf_u3;
    a.b1 = b_u1; a.b2 = b_u2; a.b3 = b_u3;
    a.out = out_user; a.out2 = nullptr; a.M = U;
    tower_k<192, 3, 0><<<(U + 255) / 256, 512, 0, stream>>>(a);
  }
}